// Round 9
// baseline (239.532 us; speedup 1.0000x reference)
//
#include <hip/hip_runtime.h>

typedef _Float16 f16;
typedef _Float16 half8 __attribute__((ext_vector_type(8)));
typedef float f32x4 __attribute__((ext_vector_type(4)));

#define NN 2048
#define BB 32
#define CINC 32
#define HH 64
#define DD 64
#define C1 96      // CIN + H
#define KI 192     // 2 * C1
#define OG 128
#define OU 64
#define WCG 24576  // OG * KI
#define WCU 12288  // OU * KI

// xg element (n, ki, b) with ki = ks*32+kk, kk = q*8+kkl:
// flat = ((((n*6+ks)*4+q)*32 + b)*8 + kkl   -> wave loads are 16B-contiguous in b
#define XGI(n, ks, b, kk) \
  ((((((size_t)(n)) * 6 + (ks)) * 4 + ((kk) >> 3)) * BB + (b)) * 8 + ((kk) & 7))

__device__ __forceinline__ f32x4 mfma16(half8 a, half8 b, f32x4 c) {
  return __builtin_amdgcn_mfma_f32_16x16x32_f16(a, b, c, 0, 0, 0);
}

typedef __attribute__((address_space(1))) const void* gas_t;
typedef __attribute__((address_space(3))) void* las_t;
__device__ __forceinline__ void gl_lds16(const void* g, void* l) {
  __builtin_amdgcn_global_load_lds((gas_t)g, (las_t)l, 16, 0, 0);
}

// XOR swizzle for 128B-row LDS tiles (rule #21: pre-swizzled source + swizzled read)
#define SWZ(row, kb) (((row) << 7) + ((kb) ^ (((row) & 7) << 4)))

// ------- LayerNorm -> e (f16) + both bias projections, one launch -------
__global__ __launch_bounds__(256) void k_ln_bias(
    const float* __restrict__ ne, const float* __restrict__ te,
    const float* __restrict__ gg, const float* __restrict__ gb,
    const float* __restrict__ ug, const float* __restrict__ ub,
    const float* __restrict__ gbp, const float* __restrict__ ubp,
    f16* __restrict__ egh, f16* __restrict__ euh,
    float* __restrict__ biasg, float* __restrict__ biasu) {
  __shared__ float esg[4][64];
  __shared__ float esu[4][64];
  int nl = threadIdx.x >> 6;
  int node = blockIdx.x * 4 + nl;
  int d = threadIdx.x & 63;
  float v = ne[node * DD + d] + te[d];
  float s = v;
  #pragma unroll
  for (int m = 1; m < 64; m <<= 1) s += __shfl_xor(s, m, 64);
  float mu = s * (1.f / 64.f);
  float df = v - mu;
  float q = df * df;
  #pragma unroll
  for (int m = 1; m < 64; m <<= 1) q += __shfl_xor(q, m, 64);
  float rs = rsqrtf(q * (1.f / 64.f) + 1e-12f);
  float base = df * rs;
  float a = base * gg[d] + gb[d];
  float b = base * ug[d] + ub[d];
  egh[node * DD + d] = (f16)a;
  euh[node * DD + d] = (f16)b;
  esg[nl][d] = a; esu[nl][d] = b;
  __syncthreads();
  #pragma unroll
  for (int i = 0; i < 3; ++i) {
    int u = i * 256 + threadIdx.x;
    int un = u / 192, oo = u % 192;
    int n2 = blockIdx.x * 4 + un;
    float acc = 0.f;
    if (oo < OG) {
      #pragma unroll 8
      for (int dd = 0; dd < 64; ++dd) acc += esg[un][dd] * gbp[dd * OG + oo];
      biasg[(size_t)n2 * OG + oo] = acc;
    } else {
      int o = oo - OG;
      #pragma unroll 8
      for (int dd = 0; dd < 64; ++dd) acc += esu[un][dd] * ubp[dd * OU + o];
      biasu[(size_t)n2 * OU + o] = acc;
    }
  }
}

// ------- wpool (d,ki,o) f32 -> wt rows r = ((ks*4+q)*O + o)*8 + kkl, cols d -------
__global__ __launch_bounds__(256) void k_wpool_t(const float* __restrict__ gwp,
                                                 const float* __restrict__ uwp,
                                                 f16* __restrict__ wtg,
                                                 f16* __restrict__ wtu) {
  const int upd = blockIdx.z;
  if (upd && blockIdx.y >= OU / 16) return;
  const float* wpool = upd ? uwp : gwp;
  f16* wt = upd ? wtu : wtg;
  const int O = upd ? OU : OG;
  __shared__ float tile[64][17];
  int ki = blockIdx.x;
  int o0 = blockIdx.y * 16;
  int t = threadIdx.x;
  const int seg = (ki >> 5) * 4 + ((ki >> 3) & 3);   // ks*4+q
  const int kkl = ki & 7;
  #pragma unroll
  for (int i = 0; i < 4; ++i) {
    int e2 = i * 256 + t;
    int d = e2 >> 4, o = e2 & 15;
    tile[d][o] = wpool[((size_t)d * KI + ki) * O + o0 + o];
  }
  __syncthreads();
  #pragma unroll
  for (int i = 0; i < 4; ++i) {
    int e2 = i * 256 + t;
    int o = e2 >> 6, d = e2 & 63;
    size_t row = ((size_t)seg * O + (o0 + o)) * 8 + kkl;
    wt[row * DD + d] = (f16)tile[d][o];
  }
}

// ------- build cm[b][c][m], xg (c<96), sth[b][m][o] f16 in one pass -------
__global__ __launch_bounds__(256) void k_build_inp(const float* __restrict__ x,
                                                   const float* __restrict__ st,
                                                   f16* __restrict__ cm,
                                                   f16* __restrict__ xg,
                                                   f16* __restrict__ sth) {
  __shared__ f16 tile[96][66];
  int mb = blockIdx.x * 64;
  int b = blockIdx.y;
  int t = threadIdx.x;
  #pragma unroll
  for (int i = 0; i < 24; ++i) {
    int e2 = i * 256 + t;  // 0..6143
    int m = e2 / 96, c = e2 % 96;
    float v = (c < CINC) ? x[((size_t)b * NN + mb + m) * CINC + c]
                         : st[((size_t)b * NN + mb + m) * HH + c - CINC];
    f16 h = (f16)v;
    tile[c][m] = h;
    xg[XGI(mb + m, c >> 5, b, c & 31)] = h;
    if (c >= CINC) sth[((size_t)b * NN + mb + m) * HH + c - CINC] = h;
  }
  __syncthreads();
  #pragma unroll
  for (int i = 0; i < 24; ++i) {
    int e2 = i * 256 + t;
    int c = e2 >> 6, m = e2 & 63;
    cm[((size_t)b * C1 + c) * NN + mb + m] = tile[c][m];
  }
}

// ---------------- zs[b][m][o] -> cand_cm[b][32+o][m] ----------------
__global__ __launch_bounds__(256) void k_transpose_zs(const f16* __restrict__ zs,
                                                      f16* __restrict__ cm) {
  __shared__ f16 tile[64][66];
  int mb = blockIdx.x * 64;
  int b = blockIdx.y;
  int t = threadIdx.x;
  #pragma unroll
  for (int i = 0; i < 16; ++i) {
    int e2 = i * 256 + t;
    int m = e2 >> 6, o = e2 & 63;
    tile[o][m] = zs[((size_t)b * NN + mb + m) * HH + o];
  }
  __syncthreads();
  #pragma unroll
  for (int i = 0; i < 16; ++i) {
    int e2 = i * 256 + t;
    int o = e2 >> 6, m = e2 & 63;
    cm[((size_t)b * C1 + CINC + o) * NN + mb + m] = tile[o][m];
  }
}

// ------- fused scores+softmax: adj[r][:] = softmax(e[r] . e^T), f16 MFMA -------
__global__ __launch_bounds__(256) void k_attn(const f16* __restrict__ eh,
                                              f16* __restrict__ adj) {
  const int r0 = blockIdx.x * 16;
  const int w = threadIdx.x >> 6, lane = threadIdx.x & 63;
  const int fr = lane & 15, fq = lane >> 4;
  __shared__ float pm[4][16], ps[4][16];
  __shared__ float fm[16], fs[16];
  const half8 a0 = *(const half8*)&eh[(size_t)(r0 + fr) * DD + fq * 8];
  const half8 a1 = *(const half8*)&eh[(size_t)(r0 + fr) * DD + 32 + fq * 8];
  float m[4], s[4];
  #pragma unroll
  for (int r = 0; r < 4; ++r) { m[r] = -3.0e38f; s[r] = 0.f; }
  for (int ct = 0; ct < 32; ++ct) {
    const int c0 = w * 512 + ct * 16;
    half8 b0 = *(const half8*)&eh[(size_t)(c0 + fr) * DD + fq * 8];
    half8 b1 = *(const half8*)&eh[(size_t)(c0 + fr) * DD + 32 + fq * 8];
    f32x4 d = mfma16(a0, b0, f32x4{0.f, 0.f, 0.f, 0.f});
    d = mfma16(a1, b1, d);
    #pragma unroll
    for (int r = 0; r < 4; ++r) {
      float mn = fmaxf(m[r], d[r]);
      s[r] = s[r] * __expf(m[r] - mn) + __expf(d[r] - mn);
      m[r] = mn;
    }
  }
  #pragma unroll
  for (int r = 0; r < 4; ++r) {
    #pragma unroll
    for (int mk = 1; mk < 16; mk <<= 1) {
      float mo = __shfl_xor(m[r], mk, 64);
      float so = __shfl_xor(s[r], mk, 64);
      float mn = fmaxf(m[r], mo);
      s[r] = s[r] * __expf(m[r] - mn) + so * __expf(mo - mn);
      m[r] = mn;
    }
  }
  if (fr == 0) {
    #pragma unroll
    for (int r = 0; r < 4; ++r) { pm[w][fq * 4 + r] = m[r]; ps[w][fq * 4 + r] = s[r]; }
  }
  __syncthreads();
  if (threadIdx.x < 16) {
    float M = -3.0e38f;
    #pragma unroll
    for (int i = 0; i < 4; ++i) M = fmaxf(M, pm[i][threadIdx.x]);
    float S = 0.f;
    #pragma unroll
    for (int i = 0; i < 4; ++i) S += ps[i][threadIdx.x] * __expf(pm[i][threadIdx.x] - M);
    fm[threadIdx.x] = M; fs[threadIdx.x] = 1.f / S;
  }
  __syncthreads();
  float Mr[4], Sr[4];
  #pragma unroll
  for (int r = 0; r < 4; ++r) { Mr[r] = fm[fq * 4 + r]; Sr[r] = fs[fq * 4 + r]; }
  for (int ct = 0; ct < 32; ++ct) {
    const int c0 = w * 512 + ct * 16;
    half8 b0 = *(const half8*)&eh[(size_t)(c0 + fr) * DD + fq * 8];
    half8 b1 = *(const half8*)&eh[(size_t)(c0 + fr) * DD + 32 + fq * 8];
    f32x4 d = mfma16(a0, b0, f32x4{0.f, 0.f, 0.f, 0.f});
    d = mfma16(a1, b1, d);
    #pragma unroll
    for (int r = 0; r < 4; ++r)
      adj[(size_t)(r0 + fq * 4 + r) * NN + c0 + fr] = (f16)(__expf(d[r] - Mr[r]) * Sr[r]);
  }
}

// ---------------- xa: xg (ki=96+l) = adj(n,m) @ cm(b*96+l, m)^T ----------------
#define BM 64
#define BN 96

__global__ __launch_bounds__(256, 4) void k_gemm_xa(const f16* __restrict__ A,
                                                    const f16* __restrict__ Bm,
                                                    f16* __restrict__ xg) {
  const int orig = blockIdx.x;          // 0..1023
  const int xcd = orig & 7, j = orig >> 3;
  const int nb = (j >> 2) * BM;
  const int by = (xcd << 2) + (j & 3);  // 4 consecutive by per XCD
  const int cb = by * BN;
  const int tid = threadIdx.x;
  const int w = tid >> 6, lane = tid & 63;
  const int wr = (w >> 1) * 32, wc = (w & 1) * 48;
  const int fr = lane & 15, fq = lane >> 4;

  const int arow = tid >> 3;                               // 0..31
  const int acolb = ((tid & 7) * 16) ^ ((arow & 7) << 4);  // pre-swizzled, j-invariant
  const char* asrc = (const char*)A + (size_t)(nb + arow) * (NN * 2) + acolb;
  const char* bsrc = (const char*)Bm + (size_t)(cb + arow) * (NN * 2) + acolb;

  __shared__ f16 Al[2][BM * 64];
  __shared__ f16 Bl[2][BN * 64];
  auto stage = [&](int buf, int kt) {   // 5 x global_load_lds per wave
    const size_t ko = (size_t)kt * 2;
    char* ad = (char*)&Al[buf][0] + (w << 10);
    char* bd = (char*)&Bl[buf][0] + (w << 10);
    gl_lds16(asrc + ko, ad);
    gl_lds16(asrc + ko + (size_t)32 * (NN * 2), ad + 4096);
    gl_lds16(bsrc + ko, bd);
    gl_lds16(bsrc + ko + (size_t)32 * (NN * 2), bd + 4096);
    gl_lds16(bsrc + ko + (size_t)64 * (NN * 2), bd + 8192);
  };

  f32x4 acc[2][3] = {};
  stage(0, 0);
  for (int kt = 0; kt < NN; kt += 64) {
    const int cur = (kt >> 6) & 1;
    if (kt + 64 < NN) {
      stage(cur ^ 1, kt + 64);
      asm volatile("s_waitcnt vmcnt(5)" ::: "memory");   // my stage(cur) landed
    } else {
      asm volatile("s_waitcnt vmcnt(0)" ::: "memory");
    }
    __builtin_amdgcn_sched_barrier(0);
    __builtin_amdgcn_s_barrier();                         // A: buf[cur] ready (all waves)
    const char* Ab = (const char*)&Al[cur][0];
    const char* Bb = (const char*)&Bl[cur][0];
    half8 af[2][2], bf[2][3];
    #pragma unroll
    for (int k0 = 0; k0 < 2; ++k0) {
      const int kb = k0 * 64 + fq * 16;
      #pragma unroll
      for (int mt = 0; mt < 2; ++mt)
        af[k0][mt] = *(const half8*)(Ab + SWZ(wr + mt * 16 + fr, kb));
      #pragma unroll
      for (int nt = 0; nt < 3; ++nt)
        bf[k0][nt] = *(const half8*)(Bb + SWZ(wc + nt * 16 + fr, kb));
    }
    asm volatile("s_waitcnt lgkmcnt(0)" ::: "memory");    // my reads of buf[cur] done
    __builtin_amdgcn_sched_barrier(0);
    __builtin_amdgcn_s_barrier();                         // B: release buf[cur] for restage
    #pragma unroll
    for (int k0 = 0; k0 < 2; ++k0)
      #pragma unroll
      for (int mt = 0; mt < 2; ++mt)
        #pragma unroll
        for (int nt = 0; nt < 3; ++nt)
          acc[mt][nt] = mfma16(af[k0][mt], bf[k0][nt], acc[mt][nt]);
  }
  #pragma unroll
  for (int mt = 0; mt < 2; ++mt)
    #pragma unroll
    for (int nt = 0; nt < 3; ++nt)
      #pragma unroll
      for (int r = 0; r < 4; ++r) {
        int n = nb + wr + mt * 16 + fq * 4 + r;
        int l = wc + nt * 16 + fr;         // 0..95 -> ki = 96+l
        xg[XGI(n, 3 + (l >> 5), by, l & 31)] = (f16)acc[mt][nt][r];
      }
}

// ---------------- W(all nodes): W[n][c] = e(n,:) . wt(c, :) ----------------
// GEMM M=2048, N=ncols, K=64. 128x128 tiles, LDS-staged, swizzled.
__global__ __launch_bounds__(256) void k_gemm_w2(const f16* __restrict__ A,
                                                 const f16* __restrict__ B,
                                                 f16* __restrict__ W, int ncols) {
  __shared__ f16 Al[128 * 64];
  __shared__ f16 Bl[128 * 64];
  const int cb = blockIdx.x * 128;
  const int nb = blockIdx.y * 128;
  const int tid = threadIdx.x;
  const int w = tid >> 6, lane = tid & 63;
  const int wr = (w >> 1) * 64, wc = (w & 1) * 64;
  const int fr = lane & 15, fq = lane >> 4;
  const int arow = tid >> 3;
  const int acolb = ((tid & 7) * 16) ^ ((arow & 7) << 4);
  const char* asrc = (const char*)A + (size_t)(nb + arow) * 128 + acolb;
  const char* bsrc = (const char*)B + (size_t)(cb + arow) * 128 + acolb;
  char* ad = (char*)Al + (w << 10);
  char* bd = (char*)Bl + (w << 10);
  #pragma unroll
  for (int j = 0; j < 4; ++j) gl_lds16(asrc + (size_t)j * 32 * 128, ad + j * 4096);
  #pragma unroll
  for (int j = 0; j < 4; ++j) gl_lds16(bsrc + (size_t)j * 32 * 128, bd + j * 4096);
  __syncthreads();
  f32x4 acc[4][4] = {};
  #pragma unroll
  for (int k0 = 0; k0 < 2; ++k0) {
    const int kb = k0 * 64 + fq * 16;
    half8 af[4], bf[4];
    #pragma unroll
    for (int mt = 0; mt < 4; ++mt)
      af[mt] = *(const half8*)((const char*)Al + SWZ(wr + mt * 16 + fr, kb));
    #pragma unroll
    for (int nt = 0; nt < 4; ++nt)
      bf[nt] = *(const half8*)((const char*)Bl + SWZ(wc + nt * 16 + fr, kb));
    #pragma unroll
    for (int mt = 0; mt < 4; ++mt)
      #pragma unroll
      for (int nt = 0; nt < 4; ++nt)
        acc[mt][nt] = mfma16(af[mt], bf[nt], acc[mt][nt]);
  }
  #pragma unroll
  for (int mt = 0; mt < 4; ++mt)
    #pragma unroll
    for (int nt = 0; nt < 4; ++nt)
      #pragma unroll
      for (int r = 0; r < 4; ++r) {
        int n = nb + wr + mt * 16 + fq * 4 + r;
        int c = cb + wc + nt * 16 + fr;
        W[(size_t)n * ncols + c] = (f16)acc[mt][nt][r];
      }
}

// ---------------- apply: LDS-staged W + xg (async, VGPR-free), then MFMA ----------------
// W row n = contiguous O*KI f16 in [ks][q][o][kkl] order; xg node n = contiguous
// KI*BB f16 in [ks][q][b][kkl] order. Stage both via global_load_lds, read back
// 16B-contiguous per lane (conflict-free).
template <bool GATE>
__global__ __launch_bounds__(256, GATE ? 2 : 4) void k_apply4(
    const f16* __restrict__ xg, const f16* __restrict__ W,
    const float* __restrict__ bias,
    const f16* __restrict__ sth,
    f16* xgw, f16* __restrict__ zs, f16* __restrict__ rbuf,
    float* __restrict__ outp) {
  constexpr int O = GATE ? OG : OU;
  constexpr int WB = O * KI * 2;           // 49152 / 24576 bytes
  constexpr int XB = KI * BB * 2;          // 12288 bytes
  constexpr int NOT_ = GATE ? 2 : 1;
  __shared__ __align__(128) char lds[WB + XB];
  const int n = blockIdx.x;
  const int tid = threadIdx.x;
  const int w = tid >> 6, lane = tid & 63;
  const int fr = lane & 15, fq = lane >> 4;

  const char* wsrc = (const char*)W + (size_t)n * WB + tid * 16;
  const char* xsrc = (const char*)xg + (size_t)n * XB + tid * 16;
  char* wdst = lds + (w << 10);            // wave-uniform; HW adds lane*16
  char* xdst = lds + WB + (w << 10);
  #pragma unroll
  for (int j = 0; j < WB / 4096; ++j) gl_lds16(wsrc + j * 4096, wdst + j * 4096);
  #pragma unroll
  for (int j = 0; j < XB / 4096; ++j) gl_lds16(xsrc + j * 4096, xdst + j * 4096);
  __syncthreads();

  const char* xl = lds + WB;
  f32x4 acc[2][NOT_] = {};
  #pragma unroll
  for (int ks = 0; ks < 6; ++ks) {
    const int seg = (ks * 4 + fq);
    half8 af0 = *(const half8*)(xl + (seg * 32 + fr) * 16);
    half8 af1 = *(const half8*)(xl + (seg * 32 + 16 + fr) * 16);
    #pragma unroll
    for (int ot = 0; ot < NOT_; ++ot) {
      const int o = (GATE ? (w * 2 + ot) : w) * 16 + fr;
      half8 bf = *(const half8*)(lds + (seg * O + o) * 16);
      acc[0][ot] = mfma16(af0, bf, acc[0][ot]);
      acc[1][ot] = mfma16(af1, bf, acc[1][ot]);
    }
  }
  #pragma unroll
  for (int mt = 0; mt < 2; ++mt)
    #pragma unroll
    for (int ot = 0; ot < NOT_; ++ot) {
      const int o = (GATE ? (w * 2 + ot) : w) * 16 + fr;
      const float bs = bias[(size_t)n * O + o];
      #pragma unroll
      for (int r = 0; r < 4; ++r) {
        int b = mt * 16 + fq * 4 + r;
        float val = acc[mt][ot][r] + bs;
        if (GATE) {
          float s = 1.f / (1.f + expf(-val));
          if (o < HH) {
            size_t bno = ((size_t)b * NN + n) * HH + o;
            float zst = s * (float)sth[bno];
            xgw[XGI(n, 1 + (o >> 5), b, o & 31)] = (f16)zst;  // ki = 32+o
            zs[bno] = (f16)zst;
          } else {
            rbuf[((size_t)b * NN + n) * HH + (o - HH)] = (f16)s;
          }
        } else {
          size_t bno = ((size_t)b * NN + n) * HH + o;
          float hc = tanhf(val);
          float rr = (float)rbuf[bno];
          outp[bno] = rr * (float)sth[bno] + (1.f - rr) * hc;
        }
      }
    }
}

extern "C" void kernel_launch(void* const* d_in, const int* in_sizes, int n_in,
                              void* d_out, int out_size, void* d_ws, size_t ws_size,
                              hipStream_t stream) {
  const float* x   = (const float*)d_in[0];
  const float* st  = (const float*)d_in[1];
  const float* ne  = (const float*)d_in[2];
  const float* te  = (const float*)d_in[3];
  const float* gwp = (const float*)d_in[4];
  const float* gbp = (const float*)d_in[5];
  const float* gg  = (const float*)d_in[6];
  const float* gb  = (const float*)d_in[7];
  const float* uwp = (const float*)d_in[8];
  const float* ubp = (const float*)d_in[9];
  const float* ug  = (const float*)d_in[10];
  const float* ub  = (const float*)d_in[11];
  float* out = (float*)d_out;

  char* wsb = (char*)d_ws;
  size_t off = 0;
  auto alloc = [&](size_t bytes) {
    char* p = wsb + off;
    off = (off + bytes + 255) & ~(size_t)255;
    return p;
  };
  f16*   egh   = (f16*)  alloc((size_t)NN * DD * 2);
  f16*   euh   = (f16*)  alloc((size_t)NN * DD * 2);
  float* biasg = (float*)alloc((size_t)NN * OG * 4);
  float* biasu = (float*)alloc((size_t)NN * OU * 4);
  f16*   wtg   = (f16*)  alloc((size_t)WCG * DD * 2);       //  3 MB
  f16*   wtu   = (f16*)  alloc((size_t)WCU * DD * 2);       // 1.5 MB
  f16*   xg    = (f16*)  alloc((size_t)NN * BB * KI * 2);   // 24 MB
  f16*   cm    = (f16*)  alloc((size_t)BB * C1 * NN * 2);   // 12 MB
  f16*   zs    = (f16*)  alloc((size_t)BB * NN * HH * 2);   //  8 MB
  f16*   rbuf  = (f16*)  alloc((size_t)BB * NN * HH * 2);   //  8 MB
  f16*   sth   = (f16*)  alloc((size_t)BB * NN * HH * 2);   //  8 MB
  f16*   adj   = (f16*)  alloc((size_t)NN * NN * 2);        //  8 MB
  f16*   W     = (f16*)  alloc((size_t)NN * WCG * 2);       // 96 MB
  (void)ws_size; (void)in_sizes; (void)n_in; (void)out_size;

  hipLaunchKernelGGL(k_ln_bias, dim3(NN / 4), dim3(256), 0, stream,
                     ne, te, gg, gb, ug, ub, gbp, ubp,
                     egh, euh, biasg, biasu);
  hipLaunchKernelGGL(k_wpool_t, dim3(KI, OG / 16, 2), dim3(256), 0, stream,
                     gwp, uwp, wtg, wtu);
  hipLaunchKernelGGL(k_build_inp, dim3(NN / 64, BB), dim3(256), 0, stream,
                     x, st, cm, xg, sth);

  // ---- gate GCN ----
  hipLaunchKernelGGL(k_attn, dim3(NN / 16), dim3(256), 0, stream, egh, adj);
  hipLaunchKernelGGL(k_gemm_xa, dim3(1024), dim3(256), 0, stream, adj, cm, xg);
  hipLaunchKernelGGL(k_gemm_w2, dim3(WCG / 128, NN / 128), dim3(256), 0, stream,
                     egh, wtg, W, WCG);
  hipLaunchKernelGGL((k_apply4<true>), dim3(NN), dim3(256), 0, stream,
                     xg, W, biasg, sth, xg, zs, rbuf, (float*)nullptr);
  hipLaunchKernelGGL(k_transpose_zs, dim3(NN / 64, BB), dim3(256), 0, stream, zs, cm);

  // ---- update GCN ----
  hipLaunchKernelGGL(k_attn, dim3(NN / 16), dim3(256), 0, stream, euh, adj);
  hipLaunchKernelGGL(k_gemm_xa, dim3(1024), dim3(256), 0, stream, adj, cm, xg);
  hipLaunchKernelGGL(k_gemm_w2, dim3(WCU / 128, NN / 128), dim3(256), 0, stream,
                     euh, wtu, W, WCU);
  hipLaunchKernelGGL((k_apply4<false>), dim3(NN), dim3(256), 0, stream,
                     xg, W, biasu, sth, (f16*)nullptr, (f16*)nullptr, rbuf, out);
}

// Round 11
// 226.845 us; speedup vs baseline: 1.0559x; 1.0559x over previous
//
#include <hip/hip_runtime.h>

typedef _Float16 f16;
typedef _Float16 half8 __attribute__((ext_vector_type(8)));
typedef float f32x4 __attribute__((ext_vector_type(4)));

#define NN 2048
#define BB 32
#define CINC 32
#define HH 64
#define DD 64
#define C1 96      // CIN + H
#define KI 192     // 2 * C1
#define OG 128
#define OU 64
#define WCG 24576  // OG * KI
#define WCU 12288  // OU * KI

// xg element (n, ki, b) with ki = ks*32+kk, kk = q*8+kkl:
// flat = ((((n*6+ks)*4+q)*32 + b)*8 + kkl   -> wave loads are 16B-contiguous in b
#define XGI(n, ks, b, kk) \
  ((((((size_t)(n)) * 6 + (ks)) * 4 + ((kk) >> 3)) * BB + (b)) * 8 + ((kk) & 7))

__device__ __forceinline__ f32x4 mfma16(half8 a, half8 b, f32x4 c) {
  return __builtin_amdgcn_mfma_f32_16x16x32_f16(a, b, c, 0, 0, 0);
}

typedef __attribute__((address_space(1))) const void* gas_t;
typedef __attribute__((address_space(3))) void* las_t;
__device__ __forceinline__ void gl_lds16(const void* g, void* l) {
  __builtin_amdgcn_global_load_lds((gas_t)g, (las_t)l, 16, 0, 0);
}

// XOR swizzle for 128B-row LDS tiles (rule #21: pre-swizzled source + swizzled read)
#define SWZ(row, kb) (((row) << 7) + ((kb) ^ (((row) & 7) << 4)))

// ------- LayerNorm -> e (f16) + both bias projections, one launch -------
__global__ __launch_bounds__(256) void k_ln_bias(
    const float* __restrict__ ne, const float* __restrict__ te,
    const float* __restrict__ gg, const float* __restrict__ gb,
    const float* __restrict__ ug, const float* __restrict__ ub,
    const float* __restrict__ gbp, const float* __restrict__ ubp,
    f16* __restrict__ egh, f16* __restrict__ euh,
    float* __restrict__ biasg, float* __restrict__ biasu) {
  __shared__ float esg[4][64];
  __shared__ float esu[4][64];
  int nl = threadIdx.x >> 6;
  int node = blockIdx.x * 4 + nl;
  int d = threadIdx.x & 63;
  float v = ne[node * DD + d] + te[d];
  float s = v;
  #pragma unroll
  for (int m = 1; m < 64; m <<= 1) s += __shfl_xor(s, m, 64);
  float mu = s * (1.f / 64.f);
  float df = v - mu;
  float q = df * df;
  #pragma unroll
  for (int m = 1; m < 64; m <<= 1) q += __shfl_xor(q, m, 64);
  float rs = rsqrtf(q * (1.f / 64.f) + 1e-12f);
  float base = df * rs;
  float a = base * gg[d] + gb[d];
  float b = base * ug[d] + ub[d];
  egh[node * DD + d] = (f16)a;
  euh[node * DD + d] = (f16)b;
  esg[nl][d] = a; esu[nl][d] = b;
  __syncthreads();
  #pragma unroll
  for (int i = 0; i < 3; ++i) {
    int u = i * 256 + threadIdx.x;
    int un = u / 192, oo = u % 192;
    int n2 = blockIdx.x * 4 + un;
    float acc = 0.f;
    if (oo < OG) {
      #pragma unroll 8
      for (int dd = 0; dd < 64; ++dd) acc += esg[un][dd] * gbp[dd * OG + oo];
      biasg[(size_t)n2 * OG + oo] = acc;
    } else {
      int o = oo - OG;
      #pragma unroll 8
      for (int dd = 0; dd < 64; ++dd) acc += esu[un][dd] * ubp[dd * OU + o];
      biasu[(size_t)n2 * OU + o] = acc;
    }
  }
}

// ------- wpool (d,ki,o) f32 -> wt rows r = (seg*O + o)*8 + kkl, cols d -------
// (seg = (ki>>5)*4 + ((ki>>3)&3), kkl = ki&7) -> W columns [ks][q][o][kkl]
__global__ __launch_bounds__(256) void k_wpool_t(const float* __restrict__ gwp,
                                                 const float* __restrict__ uwp,
                                                 f16* __restrict__ wtg,
                                                 f16* __restrict__ wtu) {
  const int upd = blockIdx.z;
  if (upd && blockIdx.y >= OU / 16) return;
  const float* wpool = upd ? uwp : gwp;
  f16* wt = upd ? wtu : wtg;
  const int O = upd ? OU : OG;
  __shared__ float tile[64][17];
  int ki = blockIdx.x;
  int o0 = blockIdx.y * 16;
  int t = threadIdx.x;
  const int seg = (ki >> 5) * 4 + ((ki >> 3) & 3);   // ks*4+q
  const int kkl = ki & 7;
  #pragma unroll
  for (int i = 0; i < 4; ++i) {
    int e2 = i * 256 + t;
    int d = e2 >> 4, o = e2 & 15;
    tile[d][o] = wpool[((size_t)d * KI + ki) * O + o0 + o];
  }
  __syncthreads();
  #pragma unroll
  for (int i = 0; i < 4; ++i) {
    int e2 = i * 256 + t;
    int o = e2 >> 6, d = e2 & 63;
    size_t row = ((size_t)seg * O + (o0 + o)) * 8 + kkl;
    wt[row * DD + d] = (f16)tile[d][o];
  }
}

// ------- build cm[b][c][m], xg (c<96), sth[b][m][o] f16 in one pass -------
__global__ __launch_bounds__(256) void k_build_inp(const float* __restrict__ x,
                                                   const float* __restrict__ st,
                                                   f16* __restrict__ cm,
                                                   f16* __restrict__ xg,
                                                   f16* __restrict__ sth) {
  __shared__ f16 tile[96][66];
  int mb = blockIdx.x * 64;
  int b = blockIdx.y;
  int t = threadIdx.x;
  #pragma unroll
  for (int i = 0; i < 24; ++i) {
    int e2 = i * 256 + t;  // 0..6143
    int m = e2 / 96, c = e2 % 96;
    float v = (c < CINC) ? x[((size_t)b * NN + mb + m) * CINC + c]
                         : st[((size_t)b * NN + mb + m) * HH + c - CINC];
    f16 h = (f16)v;
    tile[c][m] = h;
    xg[XGI(mb + m, c >> 5, b, c & 31)] = h;
    if (c >= CINC) sth[((size_t)b * NN + mb + m) * HH + c - CINC] = h;
  }
  __syncthreads();
  #pragma unroll
  for (int i = 0; i < 24; ++i) {
    int e2 = i * 256 + t;
    int c = e2 >> 6, m = e2 & 63;
    cm[((size_t)b * C1 + c) * NN + mb + m] = tile[c][m];
  }
}

// ---------------- zs[b][m][o] -> cand_cm[b][32+o][m] ----------------
__global__ __launch_bounds__(256) void k_transpose_zs(const f16* __restrict__ zs,
                                                      f16* __restrict__ cm) {
  __shared__ f16 tile[64][66];
  int mb = blockIdx.x * 64;
  int b = blockIdx.y;
  int t = threadIdx.x;
  #pragma unroll
  for (int i = 0; i < 16; ++i) {
    int e2 = i * 256 + t;
    int m = e2 >> 6, o = e2 & 63;
    tile[o][m] = zs[((size_t)b * NN + mb + m) * HH + o];
  }
  __syncthreads();
  #pragma unroll
  for (int i = 0; i < 16; ++i) {
    int e2 = i * 256 + t;
    int o = e2 >> 6, m = e2 & 63;
    cm[((size_t)b * C1 + CINC + o) * NN + mb + m] = tile[o][m];
  }
}

// ------- fused scores+softmax: adj[r][:] = softmax(e[r] . e^T), f16 MFMA -------
__global__ __launch_bounds__(256) void k_attn(const f16* __restrict__ eh,
                                              f16* __restrict__ adj) {
  const int r0 = blockIdx.x * 16;
  const int w = threadIdx.x >> 6, lane = threadIdx.x & 63;
  const int fr = lane & 15, fq = lane >> 4;
  __shared__ float pm[4][16], ps[4][16];
  __shared__ float fm[16], fs[16];
  const half8 a0 = *(const half8*)&eh[(size_t)(r0 + fr) * DD + fq * 8];
  const half8 a1 = *(const half8*)&eh[(size_t)(r0 + fr) * DD + 32 + fq * 8];
  float m[4], s[4];
  #pragma unroll
  for (int r = 0; r < 4; ++r) { m[r] = -3.0e38f; s[r] = 0.f; }
  for (int ct = 0; ct < 32; ++ct) {
    const int c0 = w * 512 + ct * 16;
    half8 b0 = *(const half8*)&eh[(size_t)(c0 + fr) * DD + fq * 8];
    half8 b1 = *(const half8*)&eh[(size_t)(c0 + fr) * DD + 32 + fq * 8];
    f32x4 d = mfma16(a0, b0, f32x4{0.f, 0.f, 0.f, 0.f});
    d = mfma16(a1, b1, d);
    #pragma unroll
    for (int r = 0; r < 4; ++r) {
      float mn = fmaxf(m[r], d[r]);
      s[r] = s[r] * __expf(m[r] - mn) + __expf(d[r] - mn);
      m[r] = mn;
    }
  }
  #pragma unroll
  for (int r = 0; r < 4; ++r) {
    #pragma unroll
    for (int mk = 1; mk < 16; mk <<= 1) {
      float mo = __shfl_xor(m[r], mk, 64);
      float so = __shfl_xor(s[r], mk, 64);
      float mn = fmaxf(m[r], mo);
      s[r] = s[r] * __expf(m[r] - mn) + so * __expf(mo - mn);
      m[r] = mn;
    }
  }
  if (fr == 0) {
    #pragma unroll
    for (int r = 0; r < 4; ++r) { pm[w][fq * 4 + r] = m[r]; ps[w][fq * 4 + r] = s[r]; }
  }
  __syncthreads();
  if (threadIdx.x < 16) {
    float M = -3.0e38f;
    #pragma unroll
    for (int i = 0; i < 4; ++i) M = fmaxf(M, pm[i][threadIdx.x]);
    float S = 0.f;
    #pragma unroll
    for (int i = 0; i < 4; ++i) S += ps[i][threadIdx.x] * __expf(pm[i][threadIdx.x] - M);
    fm[threadIdx.x] = M; fs[threadIdx.x] = 1.f / S;
  }
  __syncthreads();
  float Mr[4], Sr[4];
  #pragma unroll
  for (int r = 0; r < 4; ++r) { Mr[r] = fm[fq * 4 + r]; Sr[r] = fs[fq * 4 + r]; }
  for (int ct = 0; ct < 32; ++ct) {
    const int c0 = w * 512 + ct * 16;
    half8 b0 = *(const half8*)&eh[(size_t)(c0 + fr) * DD + fq * 8];
    half8 b1 = *(const half8*)&eh[(size_t)(c0 + fr) * DD + 32 + fq * 8];
    f32x4 d = mfma16(a0, b0, f32x4{0.f, 0.f, 0.f, 0.f});
    d = mfma16(a1, b1, d);
    #pragma unroll
    for (int r = 0; r < 4; ++r)
      adj[(size_t)(r0 + fq * 4 + r) * NN + c0 + fr] = (f16)(__expf(d[r] - Mr[r]) * Sr[r]);
  }
}

// ---------------- xa: xg (ki=96+l) = adj(n,m) @ cm(b*96+l, m)^T ----------------
#define BM 64
#define BN 96

__global__ __launch_bounds__(256, 4) void k_gemm_xa(const f16* __restrict__ A,
                                                    const f16* __restrict__ Bm,
                                                    f16* __restrict__ xg) {
  const int orig = blockIdx.x;          // 0..1023
  const int xcd = orig & 7, j = orig >> 3;
  const int nb = (j >> 2) * BM;
  const int by = (xcd << 2) + (j & 3);  // 4 consecutive by per XCD
  const int cb = by * BN;
  const int tid = threadIdx.x;
  const int w = tid >> 6, lane = tid & 63;
  const int wr = (w >> 1) * 32, wc = (w & 1) * 48;
  const int fr = lane & 15, fq = lane >> 4;

  const int arow = tid >> 3;                               // 0..31
  const int acolb = ((tid & 7) * 16) ^ ((arow & 7) << 4);  // pre-swizzled, j-invariant
  const char* asrc = (const char*)A + (size_t)(nb + arow) * (NN * 2) + acolb;
  const char* bsrc = (const char*)Bm + (size_t)(cb + arow) * (NN * 2) + acolb;

  __shared__ f16 Al[2][BM * 64];
  __shared__ f16 Bl[2][BN * 64];
  auto stage = [&](int buf, int kt) {   // 5 x global_load_lds per wave
    const size_t ko = (size_t)kt * 2;
    char* ad = (char*)&Al[buf][0] + (w << 10);
    char* bd = (char*)&Bl[buf][0] + (w << 10);
    gl_lds16(asrc + ko, ad);
    gl_lds16(asrc + ko + (size_t)32 * (NN * 2), ad + 4096);
    gl_lds16(bsrc + ko, bd);
    gl_lds16(bsrc + ko + (size_t)32 * (NN * 2), bd + 4096);
    gl_lds16(bsrc + ko + (size_t)64 * (NN * 2), bd + 8192);
  };

  f32x4 acc[2][3] = {};
  stage(0, 0);
  for (int kt = 0; kt < NN; kt += 64) {
    const int cur = (kt >> 6) & 1;
    if (kt + 64 < NN) {
      stage(cur ^ 1, kt + 64);
      asm volatile("s_waitcnt vmcnt(5)" ::: "memory");   // my stage(cur) landed
    } else {
      asm volatile("s_waitcnt vmcnt(0)" ::: "memory");
    }
    __builtin_amdgcn_sched_barrier(0);
    __builtin_amdgcn_s_barrier();                         // A: buf[cur] ready (all waves)
    const char* Ab = (const char*)&Al[cur][0];
    const char* Bb = (const char*)&Bl[cur][0];
    half8 af[2][2], bf[2][3];
    #pragma unroll
    for (int k0 = 0; k0 < 2; ++k0) {
      const int kb = k0 * 64 + fq * 16;
      #pragma unroll
      for (int mt = 0; mt < 2; ++mt)
        af[k0][mt] = *(const half8*)(Ab + SWZ(wr + mt * 16 + fr, kb));
      #pragma unroll
      for (int nt = 0; nt < 3; ++nt)
        bf[k0][nt] = *(const half8*)(Bb + SWZ(wc + nt * 16 + fr, kb));
    }
    asm volatile("s_waitcnt lgkmcnt(0)" ::: "memory");    // my reads of buf[cur] done
    __builtin_amdgcn_sched_barrier(0);
    __builtin_amdgcn_s_barrier();                         // B: release buf[cur] for restage
    #pragma unroll
    for (int k0 = 0; k0 < 2; ++k0)
      #pragma unroll
      for (int mt = 0; mt < 2; ++mt)
        #pragma unroll
        for (int nt = 0; nt < 3; ++nt)
          acc[mt][nt] = mfma16(af[k0][mt], bf[k0][nt], acc[mt][nt]);
  }
  #pragma unroll
  for (int mt = 0; mt < 2; ++mt)
    #pragma unroll
    for (int nt = 0; nt < 3; ++nt)
      #pragma unroll
      for (int r = 0; r < 4; ++r) {
        int n = nb + wr + mt * 16 + fq * 4 + r;
        int l = wc + nt * 16 + fr;         // 0..95 -> ki = 96+l
        xg[XGI(n, 3 + (l >> 5), by, l & 31)] = (f16)acc[mt][nt][r];
      }
}

// ---------------- W(all nodes): W[n][c] = e(n,:) . wt(c, :) ----------------
// GEMM M=2048, N=ncols, K=64. 128x128 tiles, LDS-staged, swizzled.
__global__ __launch_bounds__(256) void k_gemm_w2(const f16* __restrict__ A,
                                                 const f16* __restrict__ B,
                                                 f16* __restrict__ W, int ncols) {
  __shared__ f16 Al[128 * 64];
  __shared__ f16 Bl[128 * 64];
  const int cb = blockIdx.x * 128;
  const int nb = blockIdx.y * 128;
  const int tid = threadIdx.x;
  const int w = tid >> 6, lane = tid & 63;
  const int wr = (w >> 1) * 64, wc = (w & 1) * 64;
  const int fr = lane & 15, fq = lane >> 4;
  const int arow = tid >> 3;
  const int acolb = ((tid & 7) * 16) ^ ((arow & 7) << 4);
  const char* asrc = (const char*)A + (size_t)(nb + arow) * 128 + acolb;
  const char* bsrc = (const char*)B + (size_t)(cb + arow) * 128 + acolb;
  char* ad = (char*)Al + (w << 10);
  char* bd = (char*)Bl + (w << 10);
  #pragma unroll
  for (int j = 0; j < 4; ++j) gl_lds16(asrc + (size_t)j * 32 * 128, ad + j * 4096);
  #pragma unroll
  for (int j = 0; j < 4; ++j) gl_lds16(bsrc + (size_t)j * 32 * 128, bd + j * 4096);
  __syncthreads();
  f32x4 acc[4][4] = {};
  #pragma unroll
  for (int k0 = 0; k0 < 2; ++k0) {
    const int kb = k0 * 64 + fq * 16;
    half8 af[4], bf[4];
    #pragma unroll
    for (int mt = 0; mt < 4; ++mt)
      af[mt] = *(const half8*)((const char*)Al + SWZ(wr + mt * 16 + fr, kb));
    #pragma unroll
    for (int nt = 0; nt < 4; ++nt)
      bf[nt] = *(const half8*)((const char*)Bl + SWZ(wc + nt * 16 + fr, kb));
    #pragma unroll
    for (int mt = 0; mt < 4; ++mt)
      #pragma unroll
      for (int nt = 0; nt < 4; ++nt)
        acc[mt][nt] = mfma16(af[mt], bf[nt], acc[mt][nt]);
  }
  #pragma unroll
  for (int mt = 0; mt < 4; ++mt)
    #pragma unroll
    for (int nt = 0; nt < 4; ++nt)
      #pragma unroll
      for (int r = 0; r < 4; ++r) {
        int n = nb + wr + mt * 16 + fq * 4 + r;
        int c = cb + wc + nt * 16 + fr;
        W[(size_t)n * ncols + c] = (f16)acc[mt][nt][r];
      }
}

// ---------------- apply: xg staged once; W pipelined per-ks through 2-buffer LDS ----------------
// Same skeleton as k_gemm_xa (counted vmcnt, 2 barriers per chunk). Single gate kernel
// (both z and r halves) as in round 8. W cols [ks][q][o][kkl]; xg [ks][q][b][kkl].
template <bool GATE>
__global__ __launch_bounds__(256, 4) void k_apply6(
    const f16* __restrict__ xg, const f16* __restrict__ W,
    const float* __restrict__ bias,
    const f16* __restrict__ sth,
    f16* xgw, f16* __restrict__ zs, f16* __restrict__ rbuf,
    float* __restrict__ outp) {
  constexpr int O = GATE ? OG : OU;
  constexpr int WS = GATE ? WCG : WCU;     // elements per node
  constexpr int CHB = O * 64;              // chunk bytes per ks (8192 / 4096)
  constexpr int CHL = CHB / 4096;          // gl_lds16 per wave per chunk (2 / 1)
  constexpr int XB = 12288;                // xg bytes per node
  constexpr int NOT_ = GATE ? 2 : 1;
  __shared__ __align__(128) char Wl[2][CHB];
  __shared__ __align__(128) char Xl[XB];
  const int n = blockIdx.x;
  const int tid = threadIdx.x;
  const int w = tid >> 6, lane = tid & 63;
  const int fr = lane & 15, fq = lane >> 4;

  const char* wbase = (const char*)W + (size_t)n * (WS * 2);
  const char* xsrc = (const char*)xg + (size_t)n * XB + tid * 16;
  char* xdst = Xl + (w << 10);
  #pragma unroll
  for (int j = 0; j < XB / 4096; ++j) gl_lds16(xsrc + j * 4096, xdst + j * 4096);
  auto stageW = [&](int buf, int ks) {
    const char* src = wbase + ks * CHB + tid * 16;
    char* dst = Wl[buf] + (w << 10);
    #pragma unroll
    for (int j = 0; j < CHL; ++j) gl_lds16(src + j * 4096, dst + j * 4096);
  };

  f32x4 acc[2][NOT_] = {};
  stageW(0, 0);
  #pragma unroll
  for (int ks = 0; ks < 6; ++ks) {
    const int cur = ks & 1;
    if (ks < 5) {
      stageW(cur ^ 1, ks + 1);
      if constexpr (GATE) asm volatile("s_waitcnt vmcnt(2)" ::: "memory");
      else                asm volatile("s_waitcnt vmcnt(1)" ::: "memory");
    } else {
      asm volatile("s_waitcnt vmcnt(0)" ::: "memory");
    }
    __builtin_amdgcn_sched_barrier(0);
    __builtin_amdgcn_s_barrier();                       // Wl[cur] + (ks==0: Xl) ready
    half8 af0 = *(const half8*)(Xl + ((ks * 4 + fq) * 32 + fr) * 16);
    half8 af1 = *(const half8*)(Xl + ((ks * 4 + fq) * 32 + 16 + fr) * 16);
    half8 bf[NOT_];
    #pragma unroll
    for (int ot = 0; ot < NOT_; ++ot) {
      const int o = (GATE ? (w * 2 + ot) : w) * 16 + fr;
      bf[ot] = *(const half8*)(Wl[cur] + (fq * O + o) * 16);
    }
    asm volatile("s_waitcnt lgkmcnt(0)" ::: "memory");  // my reads of Wl[cur] done
    __builtin_amdgcn_sched_barrier(0);
    __builtin_amdgcn_s_barrier();                       // release Wl[cur] for restage
    #pragma unroll
    for (int ot = 0; ot < NOT_; ++ot) {
      acc[0][ot] = mfma16(af0, bf[ot], acc[0][ot]);
      acc[1][ot] = mfma16(af1, bf[ot], acc[1][ot]);
    }
  }
  #pragma unroll
  for (int mt = 0; mt < 2; ++mt)
    #pragma unroll
    for (int ot = 0; ot < NOT_; ++ot) {
      const int o = (GATE ? (w * 2 + ot) : w) * 16 + fr;
      const float bs = bias[(size_t)n * O + o];
      #pragma unroll
      for (int r = 0; r < 4; ++r) {
        int b = mt * 16 + fq * 4 + r;
        float val = acc[mt][ot][r] + bs;
        if (GATE) {
          float s = 1.f / (1.f + expf(-val));
          if (o < HH) {
            size_t bno = ((size_t)b * NN + n) * HH + o;
            float zst = s * (float)sth[bno];
            xgw[XGI(n, 1 + (o >> 5), b, o & 31)] = (f16)zst;  // ki = 32+o
            zs[bno] = (f16)zst;
          } else {
            rbuf[((size_t)b * NN + n) * HH + (o - HH)] = (f16)s;
          }
        } else {
          size_t bno = ((size_t)b * NN + n) * HH + o;
          float hc = tanhf(val);
          float rr = (float)rbuf[bno];
          outp[bno] = rr * (float)sth[bno] + (1.f - rr) * hc;
        }
      }
    }
}

extern "C" void kernel_launch(void* const* d_in, const int* in_sizes, int n_in,
                              void* d_out, int out_size, void* d_ws, size_t ws_size,
                              hipStream_t stream) {
  const float* x   = (const float*)d_in[0];
  const float* st  = (const float*)d_in[1];
  const float* ne  = (const float*)d_in[2];
  const float* te  = (const float*)d_in[3];
  const float* gwp = (const float*)d_in[4];
  const float* gbp = (const float*)d_in[5];
  const float* gg  = (const float*)d_in[6];
  const float* gb  = (const float*)d_in[7];
  const float* uwp = (const float*)d_in[8];
  const float* ubp = (const float*)d_in[9];
  const float* ug  = (const float*)d_in[10];
  const float* ub  = (const float*)d_in[11];
  float* out = (float*)d_out;

  char* wsb = (char*)d_ws;
  size_t off = 0;
  auto alloc = [&](size_t bytes) {
    char* p = wsb + off;
    off = (off + bytes + 255) & ~(size_t)255;
    return p;
  };
  f16*   egh   = (f16*)  alloc((size_t)NN * DD * 2);
  f16*   euh   = (f16*)  alloc((size_t)NN * DD * 2);
  float* biasg = (float*)alloc((size_t)NN * OG * 4);
  float* biasu = (float*)alloc((size_t)NN * OU * 4);
  f16*   wtg   = (f16*)  alloc((size_t)WCG * DD * 2);       //  3 MB
  f16*   wtu   = (f16*)  alloc((size_t)WCU * DD * 2);       // 1.5 MB
  f16*   xg    = (f16*)  alloc((size_t)NN * BB * KI * 2);   // 24 MB
  f16*   cm    = (f16*)  alloc((size_t)BB * C1 * NN * 2);   // 12 MB
  f16*   zs    = (f16*)  alloc((size_t)BB * NN * HH * 2);   //  8 MB
  f16*   rbuf  = (f16*)  alloc((size_t)BB * NN * HH * 2);   //  8 MB
  f16*   sth   = (f16*)  alloc((size_t)BB * NN * HH * 2);   //  8 MB
  f16*   adj   = (f16*)  alloc((size_t)NN * NN * 2);        //  8 MB
  f16*   W     = (f16*)  alloc((size_t)NN * WCG * 2);       // 96 MB
  (void)ws_size; (void)in_sizes; (void)n_in; (void)out_size;

  hipLaunchKernelGGL(k_ln_bias, dim3(NN / 4), dim3(256), 0, stream,
                     ne, te, gg, gb, ug, ub, gbp, ubp,
                     egh, euh, biasg, biasu);
  hipLaunchKernelGGL(k_wpool_t, dim3(KI, OG / 16, 2), dim3(256), 0, stream,
                     gwp, uwp, wtg, wtu);
  hipLaunchKernelGGL(k_build_inp, dim3(NN / 64, BB), dim3(256), 0, stream,
                     x, st, cm, xg, sth);

  // ---- gate GCN ----
  hipLaunchKernelGGL(k_attn, dim3(NN / 16), dim3(256), 0, stream, egh, adj);
  hipLaunchKernelGGL(k_gemm_xa, dim3(1024), dim3(256), 0, stream, adj, cm, xg);
  hipLaunchKernelGGL(k_gemm_w2, dim3(WCG / 128, NN / 128), dim3(256), 0, stream,
                     egh, wtg, W, WCG);
  hipLaunchKernelGGL((k_apply6<true>), dim3(NN), dim3(256), 0, stream,
                     xg, W, biasg, sth, xg, zs, rbuf, (float*)nullptr);
  hipLaunchKernelGGL(k_transpose_zs, dim3(NN / 64, BB), dim3(256), 0, stream, zs, cm);

  // ---- update GCN ----
  hipLaunchKernelGGL(k_attn, dim3(NN / 16), dim3(256), 0, stream, euh, adj);
  hipLaunchKernelGGL(k_gemm_xa, dim3(1024), dim3(256), 0, stream, adj, cm, xg);
  hipLaunchKernelGGL(k_gemm_w2, dim3(WCU / 128, NN / 128), dim3(256), 0, stream,
                     euh, wtu, W, WCU);
  hipLaunchKernelGGL((k_apply6<false>), dim3(NN), dim3(256), 0, stream,
                     xg, W, biasu, sth, (f16*)nullptr, (f16*)nullptr, rbuf, out);
}